// Round 9
// baseline (3470.596 us; speedup 1.0000x reference)
//
#include <hip/hip_runtime.h>

typedef __attribute__((ext_vector_type(8))) short bf16x8;
typedef __attribute__((ext_vector_type(4))) float f32x4;

// Problem constants
#define B_   16
#define C_   64
#define H_   64
#define W_   64
#define HD_  128
#define K_   320      // C + 2*HD
#define SW_  127      // H+W-1

// Decomposition: 64 blocks = 64 col-clusters (16 cols each), all 128 hd per block
#define NCG   64      // clusters
#define TC    16      // cols per cluster
#define NT    640     // threads per block (10 waves)
#define NKT   10      // K/32 k-tiles
#define SSTR  19      // Ss row stride (17 slots + pad)

// Workspace layout (float offsets)
#define BX   262144                 // boundary exchange: [parity][cluster][{h,c}][128] = 32768 floats
#define CNT  524288                 // 64 counters, stride 32 ints
#define GCNT (524288 + 2048)
#define AFB  528384                 // A-fragments: 204800 floats (hi+lo bf16 pairs)
#define XT   (528384 + 204800)      // xT: B*H*W*C = 4194304 floats
#define XT_N 4194304LL
#define WS_MIN   ((long long)XT)
#define WS_XT    ((long long)XT + XT_N)

__device__ __forceinline__ float sigm(float v) { return 1.f / (1.f + __expf(-v)); }
__device__ __forceinline__ float tanh_fast(float v) {
    float e = __expf(2.f * v);
    return 1.f - 2.f / (e + 1.f);
}

// Flags: relaxed agent-scope atomics (coherence point).
__device__ __forceinline__ int rload(int* p) {
    return __hip_atomic_load(p, __ATOMIC_RELAXED, __HIP_MEMORY_SCOPE_AGENT);
}
__device__ __forceinline__ void rbump(int* p) {
    __hip_atomic_fetch_add(p, 1, __ATOMIC_RELAXED, __HIP_MEMORY_SCOPE_AGENT);
}
__device__ __forceinline__ void wait_ge(int* p, int tgt) {
    while (rload(p) < tgt) { }       // busy poll
    __atomic_signal_fence(__ATOMIC_ACQUIRE);
}

// Coherence-point (sc0 sc1) data ops: bypass L1/L2; rest of L2 stays warm.
__device__ __forceinline__ f32x4 ld4_sc(const float* p) {
    f32x4 v;
    asm volatile("global_load_dwordx4 %0, %1, off sc0 sc1\n\ts_waitcnt vmcnt(0)"
                 : "=v"(v) : "v"(p) : "memory");
    return v;
}
__device__ __forceinline__ void st4x2_sc(float* p1, f32x4 v1, float* p2, f32x4 v2) {
    asm volatile("global_store_dwordx4 %0, %1, off sc0 sc1\n\t"
                 "global_store_dwordx4 %2, %3, off sc0 sc1\n\t"
                 "s_waitcnt vmcnt(0)"
                 :: "v"(p1), "v"(v1), "v"(p2), "v"(v2) : "memory");
}

__device__ __forceinline__ uint bf16hi(uint u) { return (u + 0x7FFFu + ((u >> 16) & 1u)) >> 16; }

// ---------------------------------------------------------------------------
// Prep: zero state+flags; build A-fragments (split-bf16, MFMA lane order),
// chunk order (ht, q, kt) so wave ht's 5 gate tiles are contiguous;
// build xT[b][hr][w][c].
//   chunk = (ht*5 + q)*10 + kt; lane element: m=lane&15, quad=lane>>4, jj in [0,8)
//   gate row o = q*128 + ht*16 + m;  k = kt*32 + quad*8 + jj
//   k<64: w_is; 64<=k<192: w_ss[...,1] (h_prev); k>=192: w_ss[...,0] (h_sh)
// ---------------------------------------------------------------------------
__global__ void lstm_prep(const float* __restrict__ x,
                          const float* __restrict__ w_is,
                          const float* __restrict__ w_ss,
                          float* __restrict__ ws, int use_xt, long long n_ws)
{
    const long long stride = (long long)gridDim.x * blockDim.x;
    const long long t0 = (long long)blockIdx.x * blockDim.x + threadIdx.x;

    long long zt = (long long)AFB; if (zt > n_ws) zt = n_ws;
    for (long long i = t0; i < zt; i += stride) ws[i] = 0.f;

    if (n_ws >= WS_MIN) {
        ushort* af = (ushort*)(ws + AFB);
        for (long long e = t0; e < 204800; e += stride) {
            int idx   = (int)e;
            int chunk = idx >> 9;           // (ht*5 + q)*10 + kt
            int lane  = (idx >> 3) & 63;
            int jj    = idx & 7;
            int ht = chunk / 50;
            int rm = chunk % 50;
            int q  = rm / 10, kt = rm % 10;
            int m = lane & 15, quad = lane >> 4;
            int o = q * HD_ + ht * 16 + m;
            int k = kt * 32 + quad * 8 + jj;
            float v;
            if (k < C_)            v = w_is[o * C_ + k];
            else if (k < C_ + HD_) v = w_ss[(o * HD_ + (k - C_)) * 2 + 1];
            else                   v = w_ss[(o * HD_ + (k - C_ - HD_)) * 2 + 0];
            uint uh = bf16hi(__float_as_uint(v));
            float rl = v - __uint_as_float(uh << 16);
            uint ul = bf16hi(__float_as_uint(rl));
            int base = chunk * 1024 + lane * 16 + jj;   // ushort units
            af[base]     = (ushort)uh;
            af[base + 8] = (ushort)ul;
        }
    }

    if (use_xt) {
        float* xt = ws + XT;
        for (long long e = t0; e < XT_N; e += stride) {
            int c  = (int)(e & 63);
            int w  = (int)((e >> 6) & 63);
            int hr = (int)((e >> 12) & 63);
            int b  = (int)(e >> 18);
            xt[e] = x[(((size_t)b * C_ + c) * H_ + hr) * W_ + w];
        }
    }
}

// ---------------------------------------------------------------------------
// Persistent kernel: 64 blocks (one per cluster), 127 diagonal steps.
// All 128 hd local -> h lives in LDS, c lives in registers. Only one boundary
// column (h+c) crosses blocks per step, via sc0sc1 + relaxed flags.
// Waves 0..7: hd-tile ht = wv, 5 gate tiles each. All 10 waves: convert (kt=wv).
// ---------------------------------------------------------------------------
__global__ void __launch_bounds__(NT) lstm_persist(
    const float* __restrict__ x,
    const float* __restrict__ ws_c,
    const float* __restrict__ b_is,
    const float* __restrict__ b_ss,
    float* __restrict__ out,
    float* __restrict__ ws,
    int use_xt)
{
    __shared__ float Ss[192 * SSTR];    // rows 0..63: x [c][slot1..16]; rows 64..191: h [i][slot0..16]
    __shared__ uint  Bf[NKT * 576];     // B-fragments: per kt, 64 lanes x (16B hi + 16B lo), swizzled
    __shared__ float cbL[HD_];          // imported left-boundary c column

    const int tid = threadIdx.x;
    const int cgp = blockIdx.x;
    const int n0  = cgp * TC;
    const int inb  = (n0 & 63) != 0;
    const int hasr = ((n0 + TC) & 63) != 0;

    int* cntp  = (int*)(ws + CNT);
    int* gcntp = (int*)(ws + GCNT);
    float* bx  = ws + BX;
    const float* xt = ws_c + XT;
    const uint4* afq = (const uint4*)(ws_c + AFB);

    const int lane = tid & 63;
    const int wv   = tid >> 6;          // wave index
    const int quad = lane >> 4;
    const int colc = lane & 15;
    const int ht   = wv;                // hd-tile for waves 0..7
    uint* bfp = &Bf[lane * 8 + ((lane >> 2) << 2)];
    const uint4* apW = afq + (size_t)(ht * 50) * 128 + lane * 2;

    // init LDS
    for (int i = tid; i < 192 * SSTR; i += NT) Ss[i] = 0.f;
    if (tid < HD_) cbL[tid] = 0.f;

    // per-lane persistent state + bias (waves 0..7)
    float creg[4] = {0.f, 0.f, 0.f, 0.f};
    float breg[5][4];
    if (wv < 8) {
        #pragma unroll
        for (int q = 0; q < 5; ++q)
            #pragma unroll
            for (int r = 0; r < 4; ++r) {
                int o = q * HD_ + ht * 16 + quad * 4 + r;
                breg[q][r] = b_is[o] + b_ss[o];
            }
    }
    __syncthreads();

    for (int j = 0; j < SW_; ++j) {
        // ---- prefetch x (state-independent) ----
        float xr[2];
        #pragma unroll
        for (int t = 0; t < 2; ++t) {
            int idx = tid + t * NT;
            xr[t] = 0.f;
            if (idx < C_ * TC) {
                int c = idx & 63, col = idx >> 6;
                int n = n0 + col, b = n >> 6, hr = n & 63;
                int w = j - hr;
                if ((unsigned)w < (unsigned)W_)
                    xr[t] = use_xt ? xt[(((size_t)b * H_ + hr) * W_ + w) * C_ + c]
                                   : x [(((size_t)b * C_ + c) * H_ + hr) * W_ + w];
            }
        }

        // ---- RAW wait: left neighbor finished step j-1 (its boundary export ready) ----
        if (j > 0 && inb && tid == 0) wait_ge(cntp + (cgp - 1) * 32, j);
        __syncthreads();

        // ---- gather: x slots + boundary import (h -> slot0, c -> cbL) ----
        #pragma unroll
        for (int t = 0; t < 2; ++t) {
            int idx = tid + t * NT;
            if (idx < C_ * TC) {
                int c = idx & 63, col = idx >> 6;
                Ss[c * SSTR + col + 1] = xr[t];
            }
        }
        if (j > 0 && inb) {
            const float* bsrc = bx + (size_t)(((j - 1) & 1) * NCG + (cgp - 1)) * 256;
            if (tid < 32) {                      // h boundary: 32 x float4
                f32x4 v = ld4_sc(bsrc + tid * 4);
                #pragma unroll
                for (int r = 0; r < 4; ++r)
                    Ss[(64 + tid * 4 + r) * SSTR + 0] = v[r];
            } else if (tid >= 64 && tid < 96) {  // c boundary
                int i4 = tid - 64;
                f32x4 v = ld4_sc(bsrc + 128 + i4 * 4);
                #pragma unroll
                for (int r = 0; r < 4; ++r)
                    cbL[i4 * 4 + r] = v[r];
            }
        }
        __syncthreads();
        if (tid == 0) rbump(gcntp + cgp * 32);   // left's step-(j-1) export consumed

        // ---- convert S panel to split-bf16 B-fragments (kt = wv, 10 waves = 10 kt) ----
        {
            int kb = wv * 32 + quad * 8;
            uint hv[4], lv[4];
            #pragma unroll
            for (int p = 0; p < 4; ++p) {
                int k0 = kb + 2 * p;
                float v0 = (k0 < 192) ? Ss[k0 * SSTR + colc + 1] : Ss[(k0 - 128) * SSTR + colc];
                int k1 = k0 + 1;
                float v1 = (k1 < 192) ? Ss[k1 * SSTR + colc + 1] : Ss[(k1 - 128) * SSTR + colc];
                uint h0 = bf16hi(__float_as_uint(v0));
                uint h1 = bf16hi(__float_as_uint(v1));
                float r0 = v0 - __uint_as_float(h0 << 16);
                float r1 = v1 - __uint_as_float(h1 << 16);
                uint l0 = bf16hi(__float_as_uint(r0));
                uint l1 = bf16hi(__float_as_uint(r1));
                hv[p] = h0 | (h1 << 16);
                lv[p] = l0 | (l1 << 16);
            }
            uint* bp = bfp + wv * 576;
            *(uint4*)bp       = make_uint4(hv[0], hv[1], hv[2], hv[3]);
            *(uint4*)(bp + 4) = make_uint4(lv[0], lv[1], lv[2], lv[3]);
        }
        __syncthreads();

        // ---- GEMM (waves 0..7): 5 gate tiles x 16 cols, K=320, 4-term split ----
        f32x4 acc[5] = {{0,0,0,0},{0,0,0,0},{0,0,0,0},{0,0,0,0},{0,0,0,0}};
        if (wv < 8) {
            #pragma unroll
            for (int kt = 0; kt < NKT; ++kt) {
                const uint* bp = bfp + kt * 576;
                uint4 hb = *(const uint4*)bp;
                uint4 lb = *(const uint4*)(bp + 4);
                bf16x8 Bh = *(bf16x8*)&hb, Bl = *(bf16x8*)&lb;
                #pragma unroll
                for (int q = 0; q < 5; ++q) {
                    uint4 ha = apW[(q * 10 + kt) * 128];
                    uint4 la = apW[(q * 10 + kt) * 128 + 1];
                    bf16x8 Ah = *(bf16x8*)&ha, Al = *(bf16x8*)&la;
                    acc[q] = __builtin_amdgcn_mfma_f32_16x16x32_bf16(Ah, Bh, acc[q], 0, 0, 0);
                    acc[q] = __builtin_amdgcn_mfma_f32_16x16x32_bf16(Ah, Bl, acc[q], 0, 0, 0);
                    acc[q] = __builtin_amdgcn_mfma_f32_16x16x32_bf16(Al, Bh, acc[q], 0, 0, 0);
                    acc[q] = __builtin_amdgcn_mfma_f32_16x16x32_bf16(Al, Bl, acc[q], 0, 0, 0);
                }
            }
        }

        // ---- WAR guard: right neighbor consumed our parity-(j&1) export (step j-2) ----
        if (j >= 2 && hasr && tid == 0) wait_ge(gcntp + (cgp + 1) * 32, j);
        __syncthreads();                          // Bf/h-panel reads done; safe to overwrite h

        // ---- epilogue in registers: gates -> c (regs), h -> LDS; boundary export ----
        float hv4[4];
        int do_out = 0, b_o = 0, hr_o = 0, w_o = 0;
        if (wv < 8) {
            int n = n0 + colc, bb = n >> 6, hr = n & 63;
            int w = j - hr;
            do_out = ((unsigned)w < (unsigned)W_);
            b_o = bb; hr_o = hr; w_o = w;
            #pragma unroll
            for (int r = 0; r < 4; ++r) {
                int hd = ht * 16 + quad * 4 + r;
                float go  = acc[0][r] + breg[0][r];
                float gfl = acc[1][r] + breg[1][r];
                float gfu = acc[2][r] + breg[2][r];
                float gi  = acc[3][r] + breg[3][r];
                float gg  = acc[4][r] + breg[4][r];
                float so = sigm(go), sfl = sigm(gfl), sfu = sigm(gfu), si = sigm(gi);
                float tg = tanh_fast(gg);
                float csh = __shfl_up(creg[r], 1, 16);   // col-1 within quad segment
                if (colc == 0) csh = cbL[hd];
                float cv = sfl * creg[r] + sfu * csh + si * tg;
                float hv = so * tanh_fast(cv);
                creg[r] = cv;
                hv4[r] = hv;
                Ss[(64 + hd) * SSTR + colc + 1] = hv;    // h panel for next step
            }
            if (colc == TC - 1) {                        // boundary export (1 waitcnt for both)
                float* bdst = bx + (size_t)((j & 1) * NCG + cgp) * 256 + ht * 16 + quad * 4;
                f32x4 hvv = {hv4[0], hv4[1], hv4[2], hv4[3]};
                f32x4 cvv = {creg[0], creg[1], creg[2], creg[3]};
                st4x2_sc(bdst, hvv, bdst + 128, cvv);
            }
        }
        __syncthreads();                                 // h writes + exports complete
        if (tid == 0) rbump(cntp + cgp * 32);            // step j finished
        if (do_out) {                                    // deferred plain-cached out stores
            #pragma unroll
            for (int r = 0; r < 4; ++r) {
                int hd = ht * 16 + quad * 4 + r;
                out[(((size_t)b_o * HD_ + hd) * H_ + hr_o) * W_ + w_o] = hv4[r];
            }
        }
    }
}

// ---------------------------------------------------------------------------
extern "C" void kernel_launch(void* const* d_in, const int* in_sizes, int n_in,
                              void* d_out, int out_size, void* d_ws, size_t ws_size,
                              hipStream_t stream)
{
    const float* x    = (const float*)d_in[0];
    const float* w_is = (const float*)d_in[1];
    const float* b_is = (const float*)d_in[2];
    const float* w_ss = (const float*)d_in[3];
    const float* b_ss = (const float*)d_in[4];
    float* out = (float*)d_out;
    float* ws  = (float*)d_ws;

    const long long n_ws = (long long)(ws_size / 4);
    const int use_xt = (n_ws >= WS_XT) ? 1 : 0;

    hipLaunchKernelGGL(lstm_prep, dim3(2048), dim3(256), 0, stream,
                       x, w_is, w_ss, ws, use_xt, n_ws);

    hipLaunchKernelGGL(lstm_persist, dim3(NCG), dim3(NT), 0, stream,
                       x, ws, b_is, b_ss, out, ws, use_xt);
}